// Round 2
// baseline (1366.432 us; speedup 1.0000x reference)
//
#include <hip/hip_runtime.h>
#include <stdint.h>

#define DEVI __device__ __forceinline__

typedef float f32x4 __attribute__((ext_vector_type(4)));
typedef short bf16x8 __attribute__((ext_vector_type(8)));

constexpr int Bq  = 16384;  // batch
constexpr int Eq  = 8;      // experts
constexpr int Cq  = 10;     // contexts
constexpr int INq = 39;     // obs dim
constexpr int INP = 64;     // padded obs dim
constexpr int H1q = 1024;
constexpr int H2q = 1024;
constexpr int HHq = 512;
constexpr int OUTq = 4;

DEVI unsigned short bf16_rne(float x){
  unsigned u = __builtin_bit_cast(unsigned, x);
  u += 0x7FFFu + ((u >> 16) & 1u);
  return (unsigned short)(u >> 16);
}
DEVI float bf16f(unsigned short h){
  unsigned u = ((unsigned)h) << 16;
  return __builtin_bit_cast(float, u);
}
// split fp32 -> bf16 hi + bf16 lo (x ~= hi+lo, ~2^-17 relative residual)
DEVI void split2(float x, unsigned short& hi, unsigned short& lo){
  hi = bf16_rne(x);
  lo = bf16_rne(x - bf16f(hi));
}

// ---------------------------------------------------------------------------
// One BK=32 K-step of the 128x128 (2x2 waves, 64x64/wave) split-bf16 GEMM.
// LDS per buffer: 4 tiles [128 rows][32 k] bf16 (8KB): 0=A_hi 1=A_lo 2=B_hi 3=B_lo.
// k-chunk slot XOR-swizzle: slot = chunk ^ ((row>>1)&3), applied on BOTH the
// global source address (writer) and the LDS read (guide rule #21).
// 3 MFMA products per (mf,nf): ah*bh + al*bh + ah*bl (al*bl ~2^-18, skipped).
// ---------------------------------------------------------------------------
DEVI void mfma_step(const unsigned short* lsb, int lane, int wm, int wn, f32x4 acc[4][4]){
  const int g = lane >> 4;
  bf16x8 ah[4], al[4];
#pragma unroll
  for (int mf = 0; mf < 4; ++mf){
    int r = wm*64 + mf*16 + (lane & 15);
    int off = r*32 + (g ^ ((r >> 1) & 3))*8;
    ah[mf] = *(const bf16x8*)(lsb + off);
    al[mf] = *(const bf16x8*)(lsb + 4096 + off);
  }
#pragma unroll
  for (int nf = 0; nf < 4; ++nf){
    int r = wn*64 + nf*16 + (lane & 15);
    int off = r*32 + (g ^ ((r >> 1) & 3))*8;
    bf16x8 bh = *(const bf16x8*)(lsb + 2*4096 + off);
    bf16x8 bl = *(const bf16x8*)(lsb + 3*4096 + off);
#pragma unroll
    for (int mf = 0; mf < 4; ++mf){
      acc[mf][nf] = __builtin_amdgcn_mfma_f32_16x16x32_bf16(ah[mf], bh, acc[mf][nf], 0, 0, 0);
      acc[mf][nf] = __builtin_amdgcn_mfma_f32_16x16x32_bf16(al[mf], bh, acc[mf][nf], 0, 0, 0);
      acc[mf][nf] = __builtin_amdgcn_mfma_f32_16x16x32_bf16(ah[mf], bl, acc[mf][nf], 0, 0, 0);
    }
  }
}

// ---------------------------------------------------------------------------
// prep: transpose + split: src fp32 [Z][R][Cc] -> dst bf16 [Z][Cc][Rpad] x2
// (rows in [R,Rpad) zero-filled; pads K 39->64 for Wb1)
// ---------------------------------------------------------------------------
__global__ void k_tsplit(const float* __restrict__ src,
                         unsigned short* __restrict__ dhi, unsigned short* __restrict__ dlo,
                         int R, int Cc, int Rpad){
  __shared__ float t[32][33];
  const int z = blockIdx.z;
  const int c0 = blockIdx.x*32, r0 = blockIdx.y*32;
  const float* s = src + (size_t)z*R*Cc;
#pragma unroll
  for (int i = 0; i < 4; ++i){
    int r = r0 + threadIdx.y + i*8;
    int cc = c0 + threadIdx.x;
    float v = (r < R && cc < Cc) ? s[(size_t)r*Cc + cc] : 0.f;
    t[threadIdx.y + i*8][threadIdx.x] = v;
  }
  __syncthreads();
  const size_t dbase = (size_t)z*Cc*Rpad;
#pragma unroll
  for (int i = 0; i < 4; ++i){
    int cc = c0 + threadIdx.y + i*8;
    int r  = r0 + threadIdx.x;
    if (cc < Cc && r < Rpad){
      unsigned short hi, lo;
      split2(t[threadIdx.x][threadIdx.y + i*8], hi, lo);
      size_t o = dbase + (size_t)cc*Rpad + r;
      dhi[o] = hi; dlo[o] = lo;
    }
  }
}

// prep: state [B][39] fp32 -> padded split [B][64] bf16 x2
__global__ void k_ssplit(const float* __restrict__ st,
                         unsigned short* __restrict__ sHi, unsigned short* __restrict__ sLo){
  int i = blockIdx.x*blockDim.x + threadIdx.x;
  if (i >= Bq*INP) return;
  int b = i >> 6, kk = i & 63;
  float v = (kk < INq) ? st[b*INq + kk] : 0.f;
  unsigned short hi, lo; split2(v, hi, lo);
  sHi[i] = hi; sLo[i] = lo;
}

// bucket chunk rows [b0,b0+Bc) by context: cnt[10], poff[10], perm[Bc] (LOCAL ids)
__global__ void k_bucket(const int* __restrict__ c, int b0, int Bc,
                         int* __restrict__ cnt, int* __restrict__ poff,
                         int* __restrict__ perm){
  __shared__ int lcnt[Cq];
  __shared__ int lcur[Cq];
  const int tid = threadIdx.x;
  if (tid < Cq) lcnt[tid] = 0;
  __syncthreads();
  for (int i = tid; i < Bc; i += blockDim.x) atomicAdd(&lcnt[c[b0 + i]], 1);
  __syncthreads();
  if (tid == 0){
    int s = 0;
    for (int k = 0; k < Cq; ++k){ poff[k] = s; lcur[k] = s; cnt[k] = lcnt[k]; s += lcnt[k]; }
  }
  __syncthreads();
  for (int i = tid; i < Bc; i += blockDim.x){
    int p = atomicAdd(&lcur[c[b0 + i]], 1);
    perm[p] = i;
  }
}

// ---------------------------------------------------------------------------
// K1: h[el][row][o] = relu(state[b0+row] @ Wb1[e0+el] + bb1), split bf16 pair.
// K=64 (2 BK=32 steps). grid (ot=8, bt=Bc/128, el=G). T14 reg-staging.
// ---------------------------------------------------------------------------
__global__ __launch_bounds__(256, 2)
void k_h(const unsigned short* __restrict__ sHi, const unsigned short* __restrict__ sLo,
         const unsigned short* __restrict__ w1Hi, const unsigned short* __restrict__ w1Lo,
         const float* __restrict__ bb1,
         unsigned short* __restrict__ hHi, unsigned short* __restrict__ hLo,
         int e0, int b0, int Bc){
  __shared__ unsigned short ls[2][4][4096];
  const int tid = threadIdx.x, lane = tid & 63, wid = tid >> 6;
  const int wm = wid >> 1, wn = wid & 1;
  const int ot = blockIdx.x, bt = blockIdx.y, el = blockIdx.z;
  const int ge = e0 + el;
  const int rl = lane >> 2, cs = lane & 3;
  const int corig = cs ^ ((rl >> 1) & 3);

  const f32x4 vz = {0.f, 0.f, 0.f, 0.f};
  f32x4 acc[4][4];
#pragma unroll
  for (int a = 0; a < 4; ++a)
#pragma unroll
    for (int b = 0; b < 4; ++b) acc[a][b] = vz;

  bf16x8 stg[8];
  auto loadS = [&](int s){
    const int k0 = s*32;
    if (wid < 2){
      const unsigned short* src = (wid == 0) ? sHi : sLo;
#pragma unroll
      for (int seg = 0; seg < 8; ++seg){
        int r = b0 + bt*128 + seg*16 + rl;
        stg[seg] = *(const bf16x8*)(src + (size_t)r*INP + k0 + corig*8);
      }
    } else {
      const unsigned short* src = (wid == 2) ? w1Hi : w1Lo;
#pragma unroll
      for (int seg = 0; seg < 8; ++seg){
        int r = ge*H1q + ot*128 + seg*16 + rl;
        stg[seg] = *(const bf16x8*)(src + (size_t)r*INP + k0 + corig*8);
      }
    }
  };
  auto writeS = [&](int buf){
    unsigned short* dst = &ls[buf][wid][0] + lane*8;
#pragma unroll
    for (int seg = 0; seg < 8; ++seg) *(bf16x8*)(dst + seg*512) = stg[seg];
  };

  loadS(0); writeS(0);
  for (int s = 0; s < 2; ++s){
    __syncthreads();
    if (s == 0) loadS(1);
    mfma_step(&ls[s][0][0], lane, wm, wn, acc);
    if (s == 0) writeS(1);
  }

  const int rbase = bt*128 + wm*64 + 4*(lane >> 4);   // local row
  const int cbase = ot*128 + wn*64 + (lane & 15);
#pragma unroll
  for (int nf = 0; nf < 4; ++nf){
    const int col = cbase + nf*16;
    const float bias = bb1[ge*H1q + col];
#pragma unroll
    for (int mf = 0; mf < 4; ++mf){
#pragma unroll
      for (int j = 0; j < 4; ++j){
        int row = rbase + mf*16 + j;
        float v = fmaxf(acc[mf][nf][j] + bias, 0.f);
        unsigned short hi, lo; split2(v, hi, lo);
        size_t o = ((size_t)el*Bc + row)*H1q + col;
        hHi[o] = hi; hLo[o] = lo;
      }
    }
  }
}

// ---------------------------------------------------------------------------
// K2 (dominant): per (ot,bt): loop experts el in chunk, feat = h_el @ Wb2T[el],
// facc += Wte[ge,c[b]] * relu(feat + bb2[ge]); f32f accumulates across chunks.
// grid (ot=8, bt=Bc/128). T14 reg-staging, double-buffered LDS.
// ---------------------------------------------------------------------------
__global__ __launch_bounds__(256, 2)
void k_moe(const unsigned short* __restrict__ hHi, const unsigned short* __restrict__ hLo,
           const unsigned short* __restrict__ w2Hi, const unsigned short* __restrict__ w2Lo,
           const float* __restrict__ Wte, const int* __restrict__ cIn,
           const float* __restrict__ bb2, float* __restrict__ f32f,
           int e0, int G, int first, int b0, int Bc){
  __shared__ unsigned short ls[2][4][4096];
  __shared__ float lWte[Eq*Cq];
  const int tid = threadIdx.x, lane = tid & 63, wid = tid >> 6;
  const int wm = wid >> 1, wn = wid & 1;
  const int ot = blockIdx.x, bt = blockIdx.y;
  if (tid < Eq*Cq) lWte[tid] = Wte[tid];

  const int rl = lane >> 2, cs = lane & 3;
  const int corig = cs ^ ((rl >> 1) & 3);
  const int rbase = bt*128 + wm*64 + 4*(lane >> 4);   // local row
  const int cbase = ot*128 + wn*64 + (lane & 15);

  int cidx[16];
#pragma unroll
  for (int mf = 0; mf < 4; ++mf)
#pragma unroll
    for (int j = 0; j < 4; ++j)
      cidx[mf*4 + j] = cIn[b0 + rbase + mf*16 + j];

  const f32x4 vz = {0.f, 0.f, 0.f, 0.f};
  f32x4 acc[4][4], facc[4][4];
#pragma unroll
  for (int a = 0; a < 4; ++a)
#pragma unroll
    for (int b = 0; b < 4; ++b){ acc[a][b] = vz; facc[a][b] = vz; }

  if (!first){
#pragma unroll
    for (int mf = 0; mf < 4; ++mf)
#pragma unroll
      for (int nf = 0; nf < 4; ++nf)
#pragma unroll
        for (int j = 0; j < 4; ++j)
          facc[mf][nf][j] = f32f[(size_t)(rbase + mf*16 + j)*H2q + cbase + nf*16];
  }

  bf16x8 stg[8];
  auto loadS = [&](int s){
    const int el = s >> 5;
    const int k0 = (s & 31)*32;
    if (wid < 2){
      const unsigned short* src = (wid == 0) ? hHi : hLo;
#pragma unroll
      for (int seg = 0; seg < 8; ++seg){
        int r = bt*128 + seg*16 + rl;
        stg[seg] = *(const bf16x8*)(src + ((size_t)el*Bc + r)*H1q + k0 + corig*8);
      }
    } else {
      const unsigned short* src = (wid == 2) ? w2Hi : w2Lo;
#pragma unroll
      for (int seg = 0; seg < 8; ++seg){
        int r = el*H2q + ot*128 + seg*16 + rl;   // slot-local expert index
        stg[seg] = *(const bf16x8*)(src + (size_t)r*H1q + k0 + corig*8);
      }
    }
  };
  auto writeS = [&](int buf){
    unsigned short* dst = &ls[buf][wid][0] + lane*8;
#pragma unroll
    for (int seg = 0; seg < 8; ++seg) *(bf16x8*)(dst + seg*512) = stg[seg];
  };

  const int total = G*32;
  loadS(0); writeS(0);
  for (int s = 0; s < total; ++s){
    __syncthreads();
    if (s + 1 < total) loadS(s + 1);
    mfma_step(&ls[s & 1][0][0], lane, wm, wn, acc);
    if (s + 1 < total) writeS((s + 1) & 1);
    if ((s & 31) == 31){                   // expert boundary: combine
      const int ge = e0 + (s >> 5);
#pragma unroll
      for (int nf = 0; nf < 4; ++nf){
        const float bias = bb2[ge*H2q + cbase + nf*16];
#pragma unroll
        for (int mf = 0; mf < 4; ++mf){
          f32x4 v = acc[mf][nf];
          acc[mf][nf] = vz;
#pragma unroll
          for (int j = 0; j < 4; ++j){
            float w = lWte[ge*Cq + cidx[mf*4 + j]];
            facc[mf][nf][j] += w * fmaxf(v[j] + bias, 0.f);
          }
        }
      }
    }
  }

#pragma unroll
  for (int mf = 0; mf < 4; ++mf)
#pragma unroll
    for (int nf = 0; nf < 4; ++nf)
#pragma unroll
      for (int j = 0; j < 4; ++j)
        f32f[(size_t)(rbase + mf*16 + j)*H2q + cbase + nf*16] = facc[mf][nf][j];
}

// f = relu(f32f), split to bf16 pair
__global__ void k_fsplit(const float* __restrict__ f32f,
                         unsigned short* __restrict__ fHi, unsigned short* __restrict__ fLo,
                         int n){
  int i = blockIdx.x*blockDim.x + threadIdx.x;
  if (i >= n) return;
  float v = fmaxf(f32f[i], 0.f);
  unsigned short hi, lo; split2(v, hi, lo);
  fHi[i] = hi; fLo[i] = lo;
}

// ---------------------------------------------------------------------------
// K3: per-context gathered GEMM y1p[pos] = relu(f[perm[pos]] @ Wh1[ct] + bh1)
// grid (ot=4, ct=10, tile=Bc/128); blocks past cnt[ct] exit. perm/f rows LOCAL.
// ---------------------------------------------------------------------------
__global__ __launch_bounds__(256, 2)
void k_head1(const unsigned short* __restrict__ fHi, const unsigned short* __restrict__ fLo,
             const unsigned short* __restrict__ whHi, const unsigned short* __restrict__ whLo,
             const float* __restrict__ bh1,
             const int* __restrict__ perm, const int* __restrict__ cnt,
             const int* __restrict__ poff,
             float* __restrict__ y1p){
  __shared__ unsigned short ls[2][4][4096];
  const int ot = blockIdx.x, ct = blockIdx.y, tile = blockIdx.z;
  const int n = cnt[ct];
  const int rem = n - tile*128;
  if (rem <= 0) return;
  const int tid = threadIdx.x, lane = tid & 63, wid = tid >> 6;
  const int wm = wid >> 1, wn = wid & 1;
  const int rl = lane >> 2, cs = lane & 3;
  const int corig = cs ^ ((rl >> 1) & 3);
  const int base = poff[ct] + tile*128;

  int prow[8];
#pragma unroll
  for (int seg = 0; seg < 8; ++seg){
    int lr = seg*16 + rl;
    prow[seg] = perm[base + (lr < rem ? lr : 0)];
  }

  const f32x4 vz = {0.f, 0.f, 0.f, 0.f};
  f32x4 acc[4][4];
#pragma unroll
  for (int a = 0; a < 4; ++a)
#pragma unroll
    for (int b = 0; b < 4; ++b) acc[a][b] = vz;

  bf16x8 stg[8];
  auto loadS = [&](int s){
    const int k0 = s*32;
    if (wid < 2){
      const unsigned short* src = (wid == 0) ? fHi : fLo;
#pragma unroll
      for (int seg = 0; seg < 8; ++seg)
        stg[seg] = *(const bf16x8*)(src + (size_t)prow[seg]*H2q + k0 + corig*8);
    } else {
      const unsigned short* src = (wid == 2) ? whHi : whLo;
#pragma unroll
      for (int seg = 0; seg < 8; ++seg){
        int r = ct*HHq + ot*128 + seg*16 + rl;
        stg[seg] = *(const bf16x8*)(src + (size_t)r*H2q + k0 + corig*8);
      }
    }
  };
  auto writeS = [&](int buf){
    unsigned short* dst = &ls[buf][wid][0] + lane*8;
#pragma unroll
    for (int seg = 0; seg < 8; ++seg) *(bf16x8*)(dst + seg*512) = stg[seg];
  };

  loadS(0); writeS(0);
  for (int s = 0; s < 32; ++s){
    __syncthreads();
    if (s + 1 < 32) loadS(s + 1);
    mfma_step(&ls[s & 1][0][0], lane, wm, wn, acc);
    if (s + 1 < 32) writeS((s + 1) & 1);
  }

  const int rloc = wm*64 + 4*(lane >> 4);
  const int cbase = ot*128 + wn*64 + (lane & 15);
#pragma unroll
  for (int nf = 0; nf < 4; ++nf){
    const int col = cbase + nf*16;
    const float bias = bh1[ct*HHq + col];
#pragma unroll
    for (int mf = 0; mf < 4; ++mf){
#pragma unroll
      for (int j = 0; j < 4; ++j){
        int lr = rloc + mf*16 + j;
        if (lr < rem)
          y1p[(size_t)(base + lr)*HHq + col] = fmaxf(acc[mf][nf][j] + bias, 0.f);
      }
    }
  }
}

// K4: a = y1 @ Wh2[ct] + bh2[ct], one wave per sample, scatter to d_out.
__global__ void k_head2(const float* __restrict__ y1p, const float* __restrict__ Wh2,
                        const float* __restrict__ bh2, const int* __restrict__ perm,
                        const int* __restrict__ cIn, float* __restrict__ out, int b0){
  const int tid = threadIdx.x, lane = tid & 63, w = tid >> 6;
  const int pos = blockIdx.x*4 + w;
  const int orig = b0 + perm[pos];
  const int ct = cIn[orig];
  const float* yrow = y1p + (size_t)pos*HHq;
  const float* wct  = Wh2 + (size_t)ct*HHq*OUTq;
  f32x4 s = {0.f, 0.f, 0.f, 0.f};
  const int kb = lane*8;
  f32x4 y0 = *(const f32x4*)(yrow + kb);
  f32x4 y1 = *(const f32x4*)(yrow + kb + 4);
#pragma unroll
  for (int t = 0; t < 4; ++t){
    f32x4 wv = *(const f32x4*)(wct + (size_t)(kb + t)*4);
    s += y0[t]*wv;
  }
#pragma unroll
  for (int t = 0; t < 4; ++t){
    f32x4 wv = *(const f32x4*)(wct + (size_t)(kb + 4 + t)*4);
    s += y1[t]*wv;
  }
#pragma unroll
  for (int o = 0; o < 4; ++o){
    float v = s[o];
#pragma unroll
    for (int d = 32; d > 0; d >>= 1) v += __shfl_xor(v, d);
    if (lane == 0) out[(size_t)orig*OUTq + o] = v + bh2[ct*OUTq + o];
  }
}

// ---------------------------------------------------------------------------
extern "C" void kernel_launch(void* const* d_in, const int* in_sizes, int n_in,
                              void* d_out, int out_size, void* d_ws, size_t ws_size,
                              hipStream_t stream){
  (void)in_sizes; (void)n_in; (void)out_size;
  const float* state = (const float*)d_in[0];
  const int*   cVec  = (const int*)  d_in[1];
  const float* Wte   = (const float*)d_in[2];
  const float* Wb1   = (const float*)d_in[3];
  const float* bb1   = (const float*)d_in[4];
  const float* Wb2   = (const float*)d_in[5];
  const float* bb2   = (const float*)d_in[6];
  const float* Wh1   = (const float*)d_in[7];
  const float* bh1   = (const float*)d_in[8];
  const float* Wh2   = (const float*)d_in[9];
  const float* bh2   = (const float*)d_in[10];
  float* out = (float*)d_out;

  auto A = [](size_t x) -> size_t { return (x + 255) & ~(size_t)255; };

  const size_t pers = 2*A((size_t)Bq*INP*2)        // sHi/sLo
                    + 2*A((size_t)Eq*H1q*INP*2)    // w1 pair
                    + 2*A((size_t)Cq*HHq*H2q*2)    // wh pair
                    + A((size_t)Bq*4) + 2*A(64);   // perm, cnt, poff

  // config ladder: (NB batch chunks, G experts per chunk), fastest first
  const int candNB[8] = {1, 1, 1, 1, 2, 4, 8, 16};
  const int candG [8] = {8, 4, 2, 1, 1, 1, 1, 1};
  int NB = 16, G = 1;
  for (int i = 0; i < 8; ++i){
    size_t Bc = (size_t)Bq / candNB[i];
    size_t w2s = 2*A((size_t)candG[i]*H2q*H1q*2);
    size_t r1a = 2*A((size_t)candG[i]*Bc*H1q*2);   // h pair
    size_t r1b = 2*A(Bc*(size_t)H2q*2);            // f pair (aliases h)
    size_t r2  = A(Bc*(size_t)H2q*4);              // f32f (y1p aliases, smaller)
    size_t need = pers + w2s + (r1a > r1b ? r1a : r1b) + r2;
    if (need <= ws_size){ NB = candNB[i]; G = candG[i]; break; }
  }
  const int Bc = Bq / NB;

  char* ws = (char*)d_ws;
  size_t p = 0;
  auto alloc = [&](size_t bytes) -> void* { void* r = ws + p; p += A(bytes); return r; };

  unsigned short* sHi  = (unsigned short*)alloc((size_t)Bq*INP*2);
  unsigned short* sLo  = (unsigned short*)alloc((size_t)Bq*INP*2);
  unsigned short* w1Hi = (unsigned short*)alloc((size_t)Eq*H1q*INP*2);
  unsigned short* w1Lo = (unsigned short*)alloc((size_t)Eq*H1q*INP*2);
  unsigned short* whHi = (unsigned short*)alloc((size_t)Cq*HHq*H2q*2);
  unsigned short* whLo = (unsigned short*)alloc((size_t)Cq*HHq*H2q*2);
  int* perm = (int*)alloc((size_t)Bq*4);
  int* cnt  = (int*)alloc(64);
  int* poff = (int*)alloc(64);
  unsigned short* w2Hi = (unsigned short*)alloc((size_t)G*H2q*H1q*2);
  unsigned short* w2Lo = (unsigned short*)alloc((size_t)G*H2q*H1q*2);
  // region1: h pair while backbone runs; f pair afterwards (h dead)
  size_t r1a = 2*A((size_t)G*Bc*H1q*2), r1b = 2*A((size_t)Bc*H2q*2);
  char* r1 = (char*)alloc((r1a > r1b ? r1a : r1b) - 256 + 1);  // alloc aligns up
  unsigned short* hHi = (unsigned short*)r1;
  unsigned short* hLo = (unsigned short*)(r1 + A((size_t)G*Bc*H1q*2));
  unsigned short* fHi = (unsigned short*)r1;
  unsigned short* fLo = (unsigned short*)(r1 + A((size_t)Bc*H2q*2));
  // region2: f32f while combining; y1p afterwards (f32f dead)
  char* r2 = (char*)alloc((size_t)Bc*H2q*4);
  float* f32f = (float*)r2;
  float* y1p  = (float*)r2;

  const dim3 tb(32, 8, 1);
  // Wh1 [C][1024k][512o] -> [C][512o][1024k]
  k_tsplit<<<dim3(16, 32, 10), tb, 0, stream>>>(Wh1, whHi, whLo, H2q, HHq, H2q);
  // Wb1 [E][39k][1024o] -> [E][1024o][64k] (zero-pad K)
  k_tsplit<<<dim3(32, 2, 8), tb, 0, stream>>>(Wb1, w1Hi, w1Lo, INq, H1q, INP);
  k_ssplit<<<(Bq*INP + 255)/256, 256, 0, stream>>>(state, sHi, sLo);

  const int nch = Eq / G;
  for (int nb = 0; nb < NB; ++nb){
    const int b0 = nb*Bc;
    k_bucket<<<1, 1024, 0, stream>>>(cVec, b0, Bc, cnt, poff, perm);
    for (int ec = 0; ec < nch; ++ec){
      const int e0 = ec*G;
      // Wb2 slice [G][1024k][1024o] -> [G][1024o][1024k]
      k_tsplit<<<dim3(32, 32, G), tb, 0, stream>>>(Wb2 + (size_t)e0*H1q*H2q,
                                                   w2Hi, w2Lo, H1q, H2q, H1q);
      k_h  <<<dim3(8, Bc/128, G), 256, 0, stream>>>(sHi, sLo, w1Hi, w1Lo, bb1,
                                                    hHi, hLo, e0, b0, Bc);
      k_moe<<<dim3(8, Bc/128, 1), 256, 0, stream>>>(hHi, hLo, w2Hi, w2Lo, Wte, cVec,
                                                    bb2, f32f, e0, G, ec == 0 ? 1 : 0,
                                                    b0, Bc);
    }
    k_fsplit<<<(Bc*H2q + 255)/256, 256, 0, stream>>>(f32f, fHi, fLo, Bc*H2q);
    k_head1<<<dim3(4, 10, Bc/128), 256, 0, stream>>>(fHi, fLo, whHi, whLo, bh1,
                                                     perm, cnt, poff, y1p);
    k_head2<<<Bc/4, 256, 0, stream>>>(y1p, Wh2, bh2, perm, cVec, out, b0);
  }
}

// Round 5
// 1282.768 us; speedup vs baseline: 1.0652x; 1.0652x over previous
//
#include <hip/hip_runtime.h>
#include <stdint.h>

#define DEVI __device__ __forceinline__

typedef float f32x4 __attribute__((ext_vector_type(4)));
typedef short bf16x8 __attribute__((ext_vector_type(8)));

constexpr int Bq  = 16384;  // batch
constexpr int Eq  = 8;      // experts
constexpr int Cq  = 10;     // contexts
constexpr int INq = 39;     // obs dim
constexpr int INP = 64;     // padded obs dim
constexpr int H1q = 1024;
constexpr int H2q = 1024;
constexpr int HHq = 512;
constexpr int OUTq = 4;

DEVI unsigned short bf16_rne(float x){
  unsigned u = __builtin_bit_cast(unsigned, x);
  u += 0x7FFFu + ((u >> 16) & 1u);
  return (unsigned short)(u >> 16);
}
DEVI float bf16f(unsigned short h){
  unsigned u = ((unsigned)h) << 16;
  return __builtin_bit_cast(float, u);
}
// split fp32 -> bf16 hi + bf16 lo (x ~= hi+lo, ~2^-17 relative residual)
DEVI void split2(float x, unsigned short& hi, unsigned short& lo){
  hi = bf16_rne(x);
  lo = bf16_rne(x - bf16f(hi));
}

// async global->LDS DMA, 16B/lane; LDS dest must be wave-uniform (lane*16 implicit)
DEVI void dma16(const unsigned short* g, unsigned short* l){
  __builtin_amdgcn_global_load_lds(
      (const __attribute__((address_space(1))) unsigned int*)g,
      (__attribute__((address_space(3))) unsigned int*)l,
      16, 0, 0);
}

// ---------------------------------------------------------------------------
// One BK=32 K-step of the 128x128 (2x2 waves, 64x64/wave) split-bf16 GEMM.
// LDS per buffer: 4 tiles [128 rows][32 k] bf16 (8KB): 0=A_hi 1=A_lo 2=B_hi 3=B_lo.
// k-chunk slot XOR-swizzle: slot = chunk ^ ((row>>1)&3), applied on BOTH the
// global source address (DMA writer) and the LDS read (guide rule #21).
// 3 MFMA products per (mf,nf): ah*bh + al*bh + ah*bl (al*bl ~2^-16, skipped).
// ---------------------------------------------------------------------------
DEVI void mfma_step(const unsigned short* lsb, int lane, int wm, int wn, f32x4 acc[4][4]){
  const int g = lane >> 4;
  bf16x8 ah[4], al[4];
#pragma unroll
  for (int mf = 0; mf < 4; ++mf){
    int r = wm*64 + mf*16 + (lane & 15);
    int off = r*32 + (g ^ ((r >> 1) & 3))*8;
    ah[mf] = *(const bf16x8*)(lsb + off);
    al[mf] = *(const bf16x8*)(lsb + 4096 + off);
  }
#pragma unroll
  for (int nf = 0; nf < 4; ++nf){
    int r = wn*64 + nf*16 + (lane & 15);
    int off = r*32 + (g ^ ((r >> 1) & 3))*8;
    bf16x8 bh = *(const bf16x8*)(lsb + 2*4096 + off);
    bf16x8 bl = *(const bf16x8*)(lsb + 3*4096 + off);
#pragma unroll
    for (int mf = 0; mf < 4; ++mf){
      acc[mf][nf] = __builtin_amdgcn_mfma_f32_16x16x32_bf16(ah[mf], bh, acc[mf][nf], 0, 0, 0);
      acc[mf][nf] = __builtin_amdgcn_mfma_f32_16x16x32_bf16(al[mf], bh, acc[mf][nf], 0, 0, 0);
      acc[mf][nf] = __builtin_amdgcn_mfma_f32_16x16x32_bf16(ah[mf], bl, acc[mf][nf], 0, 0, 0);
    }
  }
}

// ---------------------------------------------------------------------------
// prep: transpose + split: src fp32 [Z][R][Cc] -> dst bf16 [Z][Cc][Rpad] x2
// ---------------------------------------------------------------------------
__global__ void k_tsplit(const float* __restrict__ src,
                         unsigned short* __restrict__ dhi, unsigned short* __restrict__ dlo,
                         int R, int Cc, int Rpad){
  __shared__ float t[32][33];
  const int z = blockIdx.z;
  const int c0 = blockIdx.x*32, r0 = blockIdx.y*32;
  const float* s = src + (size_t)z*R*Cc;
#pragma unroll
  for (int i = 0; i < 4; ++i){
    int r = r0 + threadIdx.y + i*8;
    int cc = c0 + threadIdx.x;
    float v = (r < R && cc < Cc) ? s[(size_t)r*Cc + cc] : 0.f;
    t[threadIdx.y + i*8][threadIdx.x] = v;
  }
  __syncthreads();
  const size_t dbase = (size_t)z*Cc*Rpad;
#pragma unroll
  for (int i = 0; i < 4; ++i){
    int cc = c0 + threadIdx.y + i*8;
    int r  = r0 + threadIdx.x;
    if (cc < Cc && r < Rpad){
      unsigned short hi, lo;
      split2(t[threadIdx.x][threadIdx.y + i*8], hi, lo);
      size_t o = dbase + (size_t)cc*Rpad + r;
      dhi[o] = hi; dlo[o] = lo;
    }
  }
}

// prep: state [B][39] fp32 -> padded split [B][64] bf16 x2
__global__ void k_ssplit(const float* __restrict__ st,
                         unsigned short* __restrict__ sHi, unsigned short* __restrict__ sLo){
  int i = blockIdx.x*blockDim.x + threadIdx.x;
  if (i >= Bq*INP) return;
  int b = i >> 6, kk = i & 63;
  float v = (kk < INq) ? st[b*INq + kk] : 0.f;
  unsigned short hi, lo; split2(v, hi, lo);
  sHi[i] = hi; sLo[i] = lo;
}

// bucket chunk rows [b0,b0+Bc) by context: cnt[10], poff[10], perm[Bc] (LOCAL ids)
__global__ void k_bucket(const int* __restrict__ c, int b0, int Bc,
                         int* __restrict__ cnt, int* __restrict__ poff,
                         int* __restrict__ perm){
  __shared__ int lcnt[Cq];
  __shared__ int lcur[Cq];
  const int tid = threadIdx.x;
  if (tid < Cq) lcnt[tid] = 0;
  __syncthreads();
  for (int i = tid; i < Bc; i += blockDim.x) atomicAdd(&lcnt[c[b0 + i]], 1);
  __syncthreads();
  if (tid == 0){
    int s = 0;
    for (int k = 0; k < Cq; ++k){ poff[k] = s; lcur[k] = s; cnt[k] = lcnt[k]; s += lcnt[k]; }
  }
  __syncthreads();
  for (int i = tid; i < Bc; i += blockDim.x){
    int p = atomicAdd(&lcur[c[b0 + i]], 1);
    perm[p] = i;
  }
}

// ---------------------------------------------------------------------------
// K1: h[el][row][o] = relu(state[b0+row] @ Wb1[e0+el] + bb1), split bf16 pair.
// K=64 (2 BK=32 steps). grid (bt=Bc/128, ot=8, el=G). global_load_lds staging.
// ---------------------------------------------------------------------------
__global__ __launch_bounds__(256, 2)
void k_h(const unsigned short* __restrict__ sHi, const unsigned short* __restrict__ sLo,
         const unsigned short* __restrict__ w1Hi, const unsigned short* __restrict__ w1Lo,
         const float* __restrict__ bb1,
         unsigned short* __restrict__ hHi, unsigned short* __restrict__ hLo,
         int e0, int b0, int Bc){
  __shared__ unsigned short ls[2][4][4096];
  const int tid = threadIdx.x, lane = tid & 63, wid = tid >> 6;
  const int wm = wid >> 1, wn = wid & 1;
  const int bt = blockIdx.x, ot = blockIdx.y, el = blockIdx.z;
  const int ge = e0 + el;
  const int rl = lane >> 2, cs = lane & 3;
  const int corig = cs ^ ((rl >> 1) & 3);

  const f32x4 vz = {0.f, 0.f, 0.f, 0.f};
  f32x4 acc[4][4];
#pragma unroll
  for (int a = 0; a < 4; ++a)
#pragma unroll
    for (int b = 0; b < 4; ++b) acc[a][b] = vz;

  auto stage = [&](int buf, int s){
    const int k0 = s*32;
    unsigned short* dst = &ls[buf][wid][0];
    if (wid < 2){
      const unsigned short* src = (wid == 0) ? sHi : sLo;
#pragma unroll
      for (int seg = 0; seg < 8; ++seg){
        int r = b0 + bt*128 + seg*16 + rl;
        dma16(src + (size_t)r*INP + k0 + corig*8, dst + seg*512);
      }
    } else {
      const unsigned short* src = (wid == 2) ? w1Hi : w1Lo;
#pragma unroll
      for (int seg = 0; seg < 8; ++seg){
        int r = ge*H1q + ot*128 + seg*16 + rl;
        dma16(src + (size_t)r*INP + k0 + corig*8, dst + seg*512);
      }
    }
  };

  stage(0, 0);
  for (int s = 0; s < 2; ++s){
    __syncthreads();                    // drains DMA (vmcnt 0) + publishes LDS
    if (s == 0) stage(1, 1);
    mfma_step(&ls[s][0][0], lane, wm, wn, acc);
  }

  const int rbase = bt*128 + wm*64 + 4*(lane >> 4);   // local row
  const int cbase = ot*128 + wn*64 + (lane & 15);
#pragma unroll
  for (int nf = 0; nf < 4; ++nf){
    const int col = cbase + nf*16;
    const float bias = bb1[ge*H1q + col];
#pragma unroll
    for (int mf = 0; mf < 4; ++mf){
#pragma unroll
      for (int j = 0; j < 4; ++j){
        int row = rbase + mf*16 + j;
        float v = fmaxf(acc[mf][nf][j] + bias, 0.f);
        unsigned short hi, lo; split2(v, hi, lo);
        size_t o = ((size_t)el*Bc + row)*H1q + col;
        hHi[o] = hi; hLo[o] = lo;
      }
    }
  }
}

// ---------------------------------------------------------------------------
// K2 (dominant): per (bt,ot): loop experts el in chunk, feat = h_el @ Wb2T[el],
// facc += Wte[ge,c[b]] * relu(feat + bb2[ge]); f32f accumulates across chunks.
// grid (bt=Bc/128, ot=8): bt-major so xcd=bt%8 -> ot-tiles of a bt-stripe share
// one XCD's L2 copy of the h rows. global_load_lds double-buffered staging.
// ---------------------------------------------------------------------------
__global__ __launch_bounds__(256, 2)
void k_moe(const unsigned short* __restrict__ hHi, const unsigned short* __restrict__ hLo,
           const unsigned short* __restrict__ w2Hi, const unsigned short* __restrict__ w2Lo,
           const float* __restrict__ Wte, const int* __restrict__ cIn,
           const float* __restrict__ bb2, float* __restrict__ f32f,
           int e0, int G, int first, int b0, int Bc){
  __shared__ unsigned short ls[2][4][4096];
  __shared__ float lWte[Eq*Cq];
  const int tid = threadIdx.x, lane = tid & 63, wid = tid >> 6;
  const int wm = wid >> 1, wn = wid & 1;
  const int bt = blockIdx.x, ot = blockIdx.y;
  if (tid < Eq*Cq) lWte[tid] = Wte[tid];

  const int rl = lane >> 2, cs = lane & 3;
  const int corig = cs ^ ((rl >> 1) & 3);
  const int rbase = bt*128 + wm*64 + 4*(lane >> 4);   // local row
  const int cbase = ot*128 + wn*64 + (lane & 15);

  int cidx[16];
#pragma unroll
  for (int mf = 0; mf < 4; ++mf)
#pragma unroll
    for (int j = 0; j < 4; ++j)
      cidx[mf*4 + j] = cIn[b0 + rbase + mf*16 + j];

  const f32x4 vz = {0.f, 0.f, 0.f, 0.f};
  f32x4 acc[4][4], facc[4][4];
#pragma unroll
  for (int a = 0; a < 4; ++a)
#pragma unroll
    for (int b = 0; b < 4; ++b){ acc[a][b] = vz; facc[a][b] = vz; }

  if (!first){
#pragma unroll
    for (int mf = 0; mf < 4; ++mf)
#pragma unroll
      for (int nf = 0; nf < 4; ++nf)
#pragma unroll
        for (int j = 0; j < 4; ++j)
          facc[mf][nf][j] = f32f[(size_t)(rbase + mf*16 + j)*H2q + cbase + nf*16];
  }

  auto stage = [&](int buf, int s){
    const int el = s >> 5;
    const int k0 = (s & 31)*32;
    unsigned short* dst = &ls[buf][wid][0];
    if (wid < 2){
      const unsigned short* src = (wid == 0) ? hHi : hLo;
#pragma unroll
      for (int seg = 0; seg < 8; ++seg){
        int r = bt*128 + seg*16 + rl;
        dma16(src + ((size_t)el*Bc + r)*H1q + k0 + corig*8, dst + seg*512);
      }
    } else {
      const unsigned short* src = (wid == 2) ? w2Hi : w2Lo;
#pragma unroll
      for (int seg = 0; seg < 8; ++seg){
        int r = el*H2q + ot*128 + seg*16 + rl;   // slot-local expert index
        dma16(src + (size_t)r*H1q + k0 + corig*8, dst + seg*512);
      }
    }
  };

  const int total = G*32;
  stage(0, 0);
  for (int s = 0; s < total; ++s){
    __syncthreads();                    // drains prev DMA (vmcnt 0) + publishes
    if (s + 1 < total) stage((s + 1) & 1, s + 1);
    mfma_step(&ls[s & 1][0][0], lane, wm, wn, acc);
    if ((s & 31) == 31){                // expert boundary: combine
      const int ge = e0 + (s >> 5);
#pragma unroll
      for (int nf = 0; nf < 4; ++nf){
        const float bias = bb2[ge*H2q + cbase + nf*16];
#pragma unroll
        for (int mf = 0; mf < 4; ++mf){
          f32x4 v = acc[mf][nf];
          acc[mf][nf] = vz;
#pragma unroll
          for (int j = 0; j < 4; ++j){
            float w = lWte[ge*Cq + cidx[mf*4 + j]];
            facc[mf][nf][j] += w * fmaxf(v[j] + bias, 0.f);
          }
        }
      }
    }
  }

#pragma unroll
  for (int mf = 0; mf < 4; ++mf)
#pragma unroll
    for (int nf = 0; nf < 4; ++nf)
#pragma unroll
      for (int j = 0; j < 4; ++j)
        f32f[(size_t)(rbase + mf*16 + j)*H2q + cbase + nf*16] = facc[mf][nf][j];
}

// f = relu(f32f), split to bf16 pair (separate kernel: f pair aliases h region,
// so it must only be written after ALL k_moe blocks finished reading h)
__global__ void k_fsplit(const float* __restrict__ f32f,
                         unsigned short* __restrict__ fHi, unsigned short* __restrict__ fLo,
                         int n){
  int i = blockIdx.x*blockDim.x + threadIdx.x;
  if (i >= n) return;
  float v = fmaxf(f32f[i], 0.f);
  unsigned short hi, lo; split2(v, hi, lo);
  fHi[i] = hi; fLo[i] = lo;
}

// ---------------------------------------------------------------------------
// K3: per-context gathered GEMM y1p[pos] = relu(f[perm[pos]] @ Wh1[ct] + bh1)
// grid (tile=Bc/128, ct=10, ot=4); blocks past cnt[ct] exit. perm/f rows LOCAL.
// ---------------------------------------------------------------------------
__global__ __launch_bounds__(256, 2)
void k_head1(const unsigned short* __restrict__ fHi, const unsigned short* __restrict__ fLo,
             const unsigned short* __restrict__ whHi, const unsigned short* __restrict__ whLo,
             const float* __restrict__ bh1,
             const int* __restrict__ perm, const int* __restrict__ cnt,
             const int* __restrict__ poff,
             float* __restrict__ y1p){
  __shared__ unsigned short ls[2][4][4096];
  const int tile = blockIdx.x, ct = blockIdx.y, ot = blockIdx.z;
  const int n = cnt[ct];
  const int rem = n - tile*128;
  if (rem <= 0) return;
  const int tid = threadIdx.x, lane = tid & 63, wid = tid >> 6;
  const int wm = wid >> 1, wn = wid & 1;
  const int rl = lane >> 2, cs = lane & 3;
  const int corig = cs ^ ((rl >> 1) & 3);
  const int base = poff[ct] + tile*128;

  int prow[8];
#pragma unroll
  for (int seg = 0; seg < 8; ++seg){
    int lr = seg*16 + rl;
    prow[seg] = perm[base + (lr < rem ? lr : 0)];
  }

  const f32x4 vz = {0.f, 0.f, 0.f, 0.f};
  f32x4 acc[4][4];
#pragma unroll
  for (int a = 0; a < 4; ++a)
#pragma unroll
    for (int b = 0; b < 4; ++b) acc[a][b] = vz;

  auto stage = [&](int buf, int s){
    const int k0 = s*32;
    unsigned short* dst = &ls[buf][wid][0];
    if (wid < 2){
      const unsigned short* src = (wid == 0) ? fHi : fLo;
#pragma unroll
      for (int seg = 0; seg < 8; ++seg)
        dma16(src + (size_t)prow[seg]*H2q + k0 + corig*8, dst + seg*512);
    } else {
      const unsigned short* src = (wid == 2) ? whHi : whLo;
#pragma unroll
      for (int seg = 0; seg < 8; ++seg){
        int r = ct*HHq + ot*128 + seg*16 + rl;
        dma16(src + (size_t)r*H2q + k0 + corig*8, dst + seg*512);
      }
    }
  };

  stage(0, 0);
  for (int s = 0; s < 32; ++s){
    __syncthreads();
    if (s + 1 < 32) stage((s + 1) & 1, s + 1);
    mfma_step(&ls[s & 1][0][0], lane, wm, wn, acc);
  }

  const int rloc = wm*64 + 4*(lane >> 4);
  const int cbase = ot*128 + wn*64 + (lane & 15);
#pragma unroll
  for (int nf = 0; nf < 4; ++nf){
    const int col = cbase + nf*16;
    const float bias = bh1[ct*HHq + col];
#pragma unroll
    for (int mf = 0; mf < 4; ++mf){
#pragma unroll
      for (int j = 0; j < 4; ++j){
        int lr = rloc + mf*16 + j;
        if (lr < rem)
          y1p[(size_t)(base + lr)*HHq + col] = fmaxf(acc[mf][nf][j] + bias, 0.f);
      }
    }
  }
}

// K4: a = y1 @ Wh2[ct] + bh2[ct], one wave per sample, scatter to d_out.
__global__ void k_head2(const float* __restrict__ y1p, const float* __restrict__ Wh2,
                        const float* __restrict__ bh2, const int* __restrict__ perm,
                        const int* __restrict__ cIn, float* __restrict__ out, int b0){
  const int tid = threadIdx.x, lane = tid & 63, w = tid >> 6;
  const int pos = blockIdx.x*4 + w;
  const int orig = b0 + perm[pos];
  const int ct = cIn[orig];
  const float* yrow = y1p + (size_t)pos*HHq;
  const float* wct  = Wh2 + (size_t)ct*HHq*OUTq;
  f32x4 s = {0.f, 0.f, 0.f, 0.f};
  const int kb = lane*8;
  f32x4 y0 = *(const f32x4*)(yrow + kb);
  f32x4 y1 = *(const f32x4*)(yrow + kb + 4);
#pragma unroll
  for (int t = 0; t < 4; ++t){
    f32x4 wv = *(const f32x4*)(wct + (size_t)(kb + t)*4);
    s += y0[t]*wv;
  }
#pragma unroll
  for (int t = 0; t < 4; ++t){
    f32x4 wv = *(const f32x4*)(wct + (size_t)(kb + 4 + t)*4);
    s += y1[t]*wv;
  }
#pragma unroll
  for (int o = 0; o < 4; ++o){
    float v = s[o];
#pragma unroll
    for (int d = 32; d > 0; d >>= 1) v += __shfl_xor(v, d);
    if (lane == 0) out[(size_t)orig*OUTq + o] = v + bh2[ct*OUTq + o];
  }
}

// ---------------------------------------------------------------------------
extern "C" void kernel_launch(void* const* d_in, const int* in_sizes, int n_in,
                              void* d_out, int out_size, void* d_ws, size_t ws_size,
                              hipStream_t stream){
  (void)in_sizes; (void)n_in; (void)out_size;
  const float* state = (const float*)d_in[0];
  const int*   cVec  = (const int*)  d_in[1];
  const float* Wte   = (const float*)d_in[2];
  const float* Wb1   = (const float*)d_in[3];
  const float* bb1   = (const float*)d_in[4];
  const float* Wb2   = (const float*)d_in[5];
  const float* bb2   = (const float*)d_in[6];
  const float* Wh1   = (const float*)d_in[7];
  const float* bh1   = (const float*)d_in[8];
  const float* Wh2   = (const float*)d_in[9];
  const float* bh2   = (const float*)d_in[10];
  float* out = (float*)d_out;

  auto A = [](size_t x) -> size_t { return (x + 255) & ~(size_t)255; };

  const size_t pers = 2*A((size_t)Bq*INP*2)        // sHi/sLo
                    + 2*A((size_t)Eq*H1q*INP*2)    // w1 pair
                    + 2*A((size_t)Cq*HHq*H2q*2)    // wh pair
                    + A((size_t)Bq*4) + 2*A(64);   // perm, cnt, poff

  // config ladder: (NB batch chunks, G experts per chunk), fastest first
  const int candNB[8] = {1, 1, 1, 1, 2, 4, 8, 16};
  const int candG [8] = {8, 4, 2, 1, 1, 1, 1, 1};
  int NB = 16, G = 1;
  for (int i = 0; i < 8; ++i){
    size_t Bc = (size_t)Bq / candNB[i];
    size_t w2s = 2*A((size_t)candG[i]*H2q*H1q*2);
    size_t r1a = 2*A((size_t)candG[i]*Bc*H1q*2);   // h pair
    size_t r1b = 2*A(Bc*(size_t)H2q*2);            // f pair (aliases h)
    size_t r2  = A(Bc*(size_t)H2q*4);              // f32f (y1p aliases, smaller)
    size_t need = pers + w2s + (r1a > r1b ? r1a : r1b) + r2;
    if (need <= ws_size){ NB = candNB[i]; G = candG[i]; break; }
  }
  const int Bc = Bq / NB;

  char* ws = (char*)d_ws;
  size_t p = 0;
  auto alloc = [&](size_t bytes) -> void* { void* r = ws + p; p += A(bytes); return r; };

  unsigned short* sHi  = (unsigned short*)alloc((size_t)Bq*INP*2);
  unsigned short* sLo  = (unsigned short*)alloc((size_t)Bq*INP*2);
  unsigned short* w1Hi = (unsigned short*)alloc((size_t)Eq*H1q*INP*2);
  unsigned short* w1Lo = (unsigned short*)alloc((size_t)Eq*H1q*INP*2);
  unsigned short* whHi = (unsigned short*)alloc((size_t)Cq*HHq*H2q*2);
  unsigned short* whLo = (unsigned short*)alloc((size_t)Cq*HHq*H2q*2);
  int* perm = (int*)alloc((size_t)Bq*4);
  int* cnt  = (int*)alloc(64);
  int* poff = (int*)alloc(64);
  unsigned short* w2Hi = (unsigned short*)alloc((size_t)G*H2q*H1q*2);
  unsigned short* w2Lo = (unsigned short*)alloc((size_t)G*H2q*H1q*2);
  // region1: h pair while backbone runs; f pair afterwards (h dead)
  size_t r1a = 2*A((size_t)G*Bc*H1q*2), r1b = 2*A((size_t)Bc*H2q*2);
  char* r1 = (char*)alloc((r1a > r1b ? r1a : r1b) - 256 + 1);  // alloc aligns up
  unsigned short* hHi = (unsigned short*)r1;
  unsigned short* hLo = (unsigned short*)(r1 + A((size_t)G*Bc*H1q*2));
  unsigned short* fHi = (unsigned short*)r1;
  unsigned short* fLo = (unsigned short*)(r1 + A((size_t)Bc*H2q*2));
  // region2: f32f while combining; y1p afterwards (f32f dead)
  char* r2 = (char*)alloc((size_t)Bc*H2q*4);
  float* f32f = (float*)r2;
  float* y1p  = (float*)r2;

  const dim3 tb(32, 8, 1);
  // Wh1 [C][1024k][512o] -> [C][512o][1024k]
  k_tsplit<<<dim3(16, 32, 10), tb, 0, stream>>>(Wh1, whHi, whLo, H2q, HHq, H2q);
  // Wb1 [E][39k][1024o] -> [E][1024o][64k] (zero-pad K)
  k_tsplit<<<dim3(32, 2, 8), tb, 0, stream>>>(Wb1, w1Hi, w1Lo, INq, H1q, INP);
  k_ssplit<<<(Bq*INP + 255)/256, 256, 0, stream>>>(state, sHi, sLo);

  const int nch = Eq / G;
  for (int nb = 0; nb < NB; ++nb){
    const int b0 = nb*Bc;
    k_bucket<<<1, 1024, 0, stream>>>(cVec, b0, Bc, cnt, poff, perm);
    for (int ec = 0; ec < nch; ++ec){
      const int e0 = ec*G;
      // Wb2 slice [G][1024k][1024o] -> [G][1024o][1024k]
      k_tsplit<<<dim3(32, 32, G), tb, 0, stream>>>(Wb2 + (size_t)e0*H1q*H2q,
                                                   w2Hi, w2Lo, H1q, H2q, H1q);
      k_h  <<<dim3(Bc/128, 8, G), 256, 0, stream>>>(sHi, sLo, w1Hi, w1Lo, bb1,
                                                    hHi, hLo, e0, b0, Bc);
      k_moe<<<dim3(Bc/128, 8), 256, 0, stream>>>(hHi, hLo, w2Hi, w2Lo, Wte, cVec,
                                                 bb2, f32f, e0, G, ec == 0 ? 1 : 0,
                                                 b0, Bc);
    }
    k_fsplit<<<(Bc*H2q + 255)/256, 256, 0, stream>>>(f32f, fHi, fLo, Bc*H2q);
    k_head1<<<dim3(Bc/128, 10, 4), 256, 0, stream>>>(fHi, fLo, whHi, whLo, bh1,
                                                     perm, cnt, poff, y1p);
    k_head2<<<Bc/4, 256, 0, stream>>>(y1p, Wh2, bh2, perm, cVec, out, b0);
  }
}

// Round 7
// 702.114 us; speedup vs baseline: 1.9462x; 1.8270x over previous
//
#include <hip/hip_runtime.h>
#include <stdint.h>

#define DEVI __device__ __forceinline__

typedef float f32x4 __attribute__((ext_vector_type(4)));
typedef short bf16x8 __attribute__((ext_vector_type(8)));

constexpr int Bq  = 16384;  // batch
constexpr int Eq  = 8;      // experts
constexpr int Cq  = 10;     // contexts
constexpr int INq = 39;     // obs dim
constexpr int INP = 64;     // padded obs dim
constexpr int H1q = 1024;
constexpr int H2q = 1024;
constexpr int HHq = 512;
constexpr int OUTq = 4;

DEVI unsigned short bf16_rne(float x){
  unsigned u = __builtin_bit_cast(unsigned, x);
  u += 0x7FFFu + ((u >> 16) & 1u);
  return (unsigned short)(u >> 16);
}

// async global->LDS DMA, 16B/lane; LDS dest wave-uniform base (+lane*16 implicit)
DEVI void dma16(const unsigned short* g, unsigned short* l){
  __builtin_amdgcn_global_load_lds(
      (const __attribute__((address_space(1))) unsigned int*)g,
      (__attribute__((address_space(3))) unsigned int*)l,
      16, 0, 0);
}

// ---------------------------------------------------------------------------
// One BK=32 K-step of the 128x128 (2x2 waves, 64x64/wave) bf16 GEMM.
// LDS per buffer: 2 tiles [128 rows][32 k] bf16 (8KB): tile0=A, tile1=B.
// k-chunk slot XOR-swizzle: slot = chunk ^ ((row>>1)&3), applied on BOTH the
// global source address (DMA writer) and the LDS read (guide rule #21).
// ---------------------------------------------------------------------------
DEVI void mfma_step1(const unsigned short* lsb, int lane, int wm, int wn, f32x4 acc[4][4]){
  const int g = lane >> 4;
  bf16x8 a[4], b[4];
#pragma unroll
  for (int mf = 0; mf < 4; ++mf){
    int r = wm*64 + mf*16 + (lane & 15);
    a[mf] = *(const bf16x8*)(lsb + r*32 + (g ^ ((r >> 1) & 3))*8);
  }
#pragma unroll
  for (int nf = 0; nf < 4; ++nf){
    int r = wn*64 + nf*16 + (lane & 15);
    b[nf] = *(const bf16x8*)(lsb + 4096 + r*32 + (g ^ ((r >> 1) & 3))*8);
  }
#pragma unroll
  for (int nf = 0; nf < 4; ++nf)
#pragma unroll
    for (int mf = 0; mf < 4; ++mf)
      acc[mf][nf] = __builtin_amdgcn_mfma_f32_16x16x32_bf16(a[mf], b[nf], acc[mf][nf], 0, 0, 0);
}

// ---------------------------------------------------------------------------
// prep: transpose + cast: src fp32 [Z][R][Cc] -> dst bf16 [Z][Cc][Rpad]
// (rows in [R,Rpad) zero-filled; pads K 39->64 for Wb1)
// ---------------------------------------------------------------------------
__global__ void k_tcast(const float* __restrict__ src, unsigned short* __restrict__ dst,
                        int R, int Cc, int Rpad){
  __shared__ float t[32][33];
  const int z = blockIdx.z;
  const int c0 = blockIdx.x*32, r0 = blockIdx.y*32;
  const float* s = src + (size_t)z*R*Cc;
#pragma unroll
  for (int i = 0; i < 4; ++i){
    int r = r0 + threadIdx.y + i*8;
    int cc = c0 + threadIdx.x;
    float v = (r < R && cc < Cc) ? s[(size_t)r*Cc + cc] : 0.f;
    t[threadIdx.y + i*8][threadIdx.x] = v;
  }
  __syncthreads();
  const size_t dbase = (size_t)z*Cc*Rpad;
#pragma unroll
  for (int i = 0; i < 4; ++i){
    int cc = c0 + threadIdx.y + i*8;
    int r  = r0 + threadIdx.x;
    if (cc < Cc && r < Rpad)
      dst[dbase + (size_t)cc*Rpad + r] = bf16_rne(t[threadIdx.x][threadIdx.y + i*8]);
  }
}

// prep: state [B][39] fp32 -> padded bf16 [B][64]
__global__ void k_scast(const float* __restrict__ st, unsigned short* __restrict__ sB){
  int i = blockIdx.x*blockDim.x + threadIdx.x;
  if (i >= Bq*INP) return;
  int b = i >> 6, kk = i & 63;
  sB[i] = bf16_rne((kk < INq) ? st[b*INq + kk] : 0.f);
}

// bucket chunk rows [b0,b0+Bc) by context: cnt[10], poff[10], perm[Bc] (LOCAL ids)
__global__ void k_bucket(const int* __restrict__ c, int b0, int Bc,
                         int* __restrict__ cnt, int* __restrict__ poff,
                         int* __restrict__ perm){
  __shared__ int lcnt[Cq];
  __shared__ int lcur[Cq];
  const int tid = threadIdx.x;
  if (tid < Cq) lcnt[tid] = 0;
  __syncthreads();
  for (int i = tid; i < Bc; i += blockDim.x) atomicAdd(&lcnt[c[b0 + i]], 1);
  __syncthreads();
  if (tid == 0){
    int s = 0;
    for (int k = 0; k < Cq; ++k){ poff[k] = s; lcur[k] = s; cnt[k] = lcnt[k]; s += lcnt[k]; }
  }
  __syncthreads();
  for (int i = tid; i < Bc; i += blockDim.x){
    int p = atomicAdd(&lcur[c[b0 + i]], 1);
    perm[p] = i;
  }
}

// ---------------------------------------------------------------------------
// K1: h[el][row][o] = relu(state[b0+row] @ Wb1[e0+el] + bb1) in bf16.
// K=64 (2 BK=32 steps). grid (bt=Bc/128, ot=8, el=G).
// ---------------------------------------------------------------------------
__global__ __launch_bounds__(256, 2)
void k_h(const unsigned short* __restrict__ sB, const unsigned short* __restrict__ w1B,
         const float* __restrict__ bb1, unsigned short* __restrict__ hB,
         int e0, int b0, int Bc){
  __shared__ unsigned short ls[2][2][4096];
  const int tid = threadIdx.x, lane = tid & 63, wid = tid >> 6;
  const int wm = wid >> 1, wn = wid & 1;
  const int bt = blockIdx.x, ot = blockIdx.y, el = blockIdx.z;
  const int ge = e0 + el;
  const int rl = lane >> 2, cs = lane & 3;
  const int corig = cs ^ ((rl >> 1) & 3);

  const f32x4 vz = {0.f, 0.f, 0.f, 0.f};
  f32x4 acc[4][4];
#pragma unroll
  for (int a = 0; a < 4; ++a)
#pragma unroll
    for (int b = 0; b < 4; ++b) acc[a][b] = vz;

  auto stage = [&](int buf, int s){
    const int k0 = s*32;
    const int half = wid & 1;
    if (wid < 2){
#pragma unroll
      for (int i = 0; i < 4; ++i){
        int seg = half*4 + i;
        int r = b0 + bt*128 + seg*16 + rl;
        dma16(sB + (size_t)r*INP + k0 + corig*8, &ls[buf][0][0] + seg*512);
      }
    } else {
#pragma unroll
      for (int i = 0; i < 4; ++i){
        int seg = half*4 + i;
        int r = ge*H1q + ot*128 + seg*16 + rl;
        dma16(w1B + (size_t)r*INP + k0 + corig*8, &ls[buf][1][0] + seg*512);
      }
    }
  };

  stage(0, 0);
  for (int s = 0; s < 2; ++s){
    __syncthreads();                    // drains DMA (vmcnt 0) + publishes LDS
    if (s == 0) stage(1, 1);
    mfma_step1(&ls[s][0][0], lane, wm, wn, acc);
  }

  const int rbase = bt*128 + wm*64 + 4*(lane >> 4);   // local row
  const int cbase = ot*128 + wn*64 + (lane & 15);
#pragma unroll
  for (int nf = 0; nf < 4; ++nf){
    const int col = cbase + nf*16;
    const float bias = bb1[ge*H1q + col];
#pragma unroll
    for (int mf = 0; mf < 4; ++mf){
#pragma unroll
      for (int j = 0; j < 4; ++j){
        int row = rbase + mf*16 + j;
        hB[((size_t)el*Bc + row)*H1q + col] = bf16_rne(fmaxf(acc[mf][nf][j] + bias, 0.f));
      }
    }
  }
}

// ---------------------------------------------------------------------------
// K2 (dominant): per (bt,ot): loop experts el in chunk, feat = h_el @ Wb2T[el],
// facc += Wte[ge,c[b]] * relu(feat + bb2[ge]).  f32f accumulates across chunks
// (untouched when G==8: first&&last).  Last chunk writes f = relu(facc) as bf16
// directly (f buffer is separate from h -> no aliasing hazard).
// grid (bt=Bc/128, ot=8): bt-major so xcd=bt%8 shares L2 copy of the h stripe.
// ---------------------------------------------------------------------------
__global__ __launch_bounds__(256, 2)
void k_moe(const unsigned short* __restrict__ hB, const unsigned short* __restrict__ w2B,
           const float* __restrict__ Wte, const int* __restrict__ cIn,
           const float* __restrict__ bb2, float* __restrict__ f32f,
           unsigned short* __restrict__ fB,
           int e0, int G, int first, int last, int b0, int Bc){
  __shared__ unsigned short ls[2][2][4096];
  __shared__ float lWte[Eq*Cq];
  const int tid = threadIdx.x, lane = tid & 63, wid = tid >> 6;
  const int wm = wid >> 1, wn = wid & 1;
  const int bt = blockIdx.x, ot = blockIdx.y;
  if (tid < Eq*Cq) lWte[tid] = Wte[tid];

  const int rl = lane >> 2, cs = lane & 3;
  const int corig = cs ^ ((rl >> 1) & 3);
  const int rbase = bt*128 + wm*64 + 4*(lane >> 4);   // local row
  const int cbase = ot*128 + wn*64 + (lane & 15);

  int cidx[16];
#pragma unroll
  for (int mf = 0; mf < 4; ++mf)
#pragma unroll
    for (int j = 0; j < 4; ++j)
      cidx[mf*4 + j] = cIn[b0 + rbase + mf*16 + j];

  const f32x4 vz = {0.f, 0.f, 0.f, 0.f};
  f32x4 acc[4][4], facc[4][4];
#pragma unroll
  for (int a = 0; a < 4; ++a)
#pragma unroll
    for (int b = 0; b < 4; ++b){ acc[a][b] = vz; facc[a][b] = vz; }

  if (!first){
#pragma unroll
    for (int mf = 0; mf < 4; ++mf)
#pragma unroll
      for (int nf = 0; nf < 4; ++nf)
#pragma unroll
        for (int j = 0; j < 4; ++j)
          facc[mf][nf][j] = f32f[(size_t)(rbase + mf*16 + j)*H2q + cbase + nf*16];
  }

  auto stage = [&](int buf, int s){
    const int el = s >> 5;
    const int k0 = (s & 31)*32;
    const int half = wid & 1;
    if (wid < 2){
#pragma unroll
      for (int i = 0; i < 4; ++i){
        int seg = half*4 + i;
        int r = bt*128 + seg*16 + rl;
        dma16(hB + ((size_t)el*Bc + r)*H1q + k0 + corig*8, &ls[buf][0][0] + seg*512);
      }
    } else {
#pragma unroll
      for (int i = 0; i < 4; ++i){
        int seg = half*4 + i;
        int r = el*H2q + ot*128 + seg*16 + rl;   // slot-local expert index
        dma16(w2B + (size_t)r*H1q + k0 + corig*8, &ls[buf][1][0] + seg*512);
      }
    }
  };

  const int total = G*32;
  stage(0, 0);
  for (int s = 0; s < total; ++s){
    __syncthreads();                    // drains prev DMA (vmcnt 0) + publishes
    if (s + 1 < total) stage((s + 1) & 1, s + 1);
    mfma_step1(&ls[s & 1][0][0], lane, wm, wn, acc);
    if ((s & 31) == 31){                // expert boundary: combine
      const int ge = e0 + (s >> 5);
#pragma unroll
      for (int nf = 0; nf < 4; ++nf){
        const float bias = bb2[ge*H2q + cbase + nf*16];
#pragma unroll
        for (int mf = 0; mf < 4; ++mf){
          f32x4 v = acc[mf][nf];
          acc[mf][nf] = vz;
#pragma unroll
          for (int j = 0; j < 4; ++j){
            float w = lWte[ge*Cq + cidx[mf*4 + j]];
            facc[mf][nf][j] += w * fmaxf(v[j] + bias, 0.f);
          }
        }
      }
    }
  }

#pragma unroll
  for (int mf = 0; mf < 4; ++mf)
#pragma unroll
    for (int nf = 0; nf < 4; ++nf)
#pragma unroll
      for (int j = 0; j < 4; ++j){
        const size_t o = (size_t)(rbase + mf*16 + j)*H2q + cbase + nf*16;
        if (last) fB[o] = bf16_rne(fmaxf(facc[mf][nf][j], 0.f));
        else      f32f[o] = facc[mf][nf][j];
      }
}

// ---------------------------------------------------------------------------
// K3: per-context gathered GEMM y1p[pos] = relu(f[perm[pos]] @ Wh1[ct] + bh1)
// grid (tile=Bc/128, ct=10, ot=4); blocks past cnt[ct] exit. perm/f rows LOCAL.
// ---------------------------------------------------------------------------
__global__ __launch_bounds__(256, 2)
void k_head1(const unsigned short* __restrict__ fB, const unsigned short* __restrict__ whB,
             const float* __restrict__ bh1,
             const int* __restrict__ perm, const int* __restrict__ cnt,
             const int* __restrict__ poff, float* __restrict__ y1p){
  __shared__ unsigned short ls[2][2][4096];
  const int tile = blockIdx.x, ct = blockIdx.y, ot = blockIdx.z;
  const int n = cnt[ct];
  const int rem = n - tile*128;
  if (rem <= 0) return;
  const int tid = threadIdx.x, lane = tid & 63, wid = tid >> 6;
  const int wm = wid >> 1, wn = wid & 1;
  const int rl = lane >> 2, cs = lane & 3;
  const int corig = cs ^ ((rl >> 1) & 3);
  const int base = poff[ct] + tile*128;

  int prow[4];
#pragma unroll
  for (int i = 0; i < 4; ++i){
    int seg = (wid & 1)*4 + i;
    int lr = seg*16 + rl;
    prow[i] = perm[base + (lr < rem ? lr : 0)];
  }

  const f32x4 vz = {0.f, 0.f, 0.f, 0.f};
  f32x4 acc[4][4];
#pragma unroll
  for (int a = 0; a < 4; ++a)
#pragma unroll
    for (int b = 0; b < 4; ++b) acc[a][b] = vz;

  auto stage = [&](int buf, int s){
    const int k0 = s*32;
    const int half = wid & 1;
    if (wid < 2){
#pragma unroll
      for (int i = 0; i < 4; ++i){
        int seg = half*4 + i;
        dma16(fB + (size_t)prow[i]*H2q + k0 + corig*8, &ls[buf][0][0] + seg*512);
      }
    } else {
#pragma unroll
      for (int i = 0; i < 4; ++i){
        int seg = half*4 + i;
        int r = ct*HHq + ot*128 + seg*16 + rl;
        dma16(whB + (size_t)r*H2q + k0 + corig*8, &ls[buf][1][0] + seg*512);
      }
    }
  };

  stage(0, 0);
  for (int s = 0; s < 32; ++s){
    __syncthreads();
    if (s + 1 < 32) stage((s + 1) & 1, s + 1);
    mfma_step1(&ls[s & 1][0][0], lane, wm, wn, acc);
  }

  const int rloc = wm*64 + 4*(lane >> 4);
  const int cbase = ot*128 + wn*64 + (lane & 15);
#pragma unroll
  for (int nf = 0; nf < 4; ++nf){
    const int col = cbase + nf*16;
    const float bias = bh1[ct*HHq + col];
#pragma unroll
    for (int mf = 0; mf < 4; ++mf){
#pragma unroll
      for (int j = 0; j < 4; ++j){
        int lr = rloc + mf*16 + j;
        if (lr < rem)
          y1p[(size_t)(base + lr)*HHq + col] = fmaxf(acc[mf][nf][j] + bias, 0.f);
      }
    }
  }
}

// K4: a = y1 @ Wh2[ct] + bh2[ct], one wave per sample, scatter to d_out. (fp32)
__global__ void k_head2(const float* __restrict__ y1p, const float* __restrict__ Wh2,
                        const float* __restrict__ bh2, const int* __restrict__ perm,
                        const int* __restrict__ cIn, float* __restrict__ out, int b0){
  const int tid = threadIdx.x, lane = tid & 63, w = tid >> 6;
  const int pos = blockIdx.x*4 + w;
  const int orig = b0 + perm[pos];
  const int ct = cIn[orig];
  const float* yrow = y1p + (size_t)pos*HHq;
  const float* wct  = Wh2 + (size_t)ct*HHq*OUTq;
  f32x4 s = {0.f, 0.f, 0.f, 0.f};
  const int kb = lane*8;
  f32x4 y0 = *(const f32x4*)(yrow + kb);
  f32x4 y1 = *(const f32x4*)(yrow + kb + 4);
#pragma unroll
  for (int t = 0; t < 4; ++t){
    f32x4 wv = *(const f32x4*)(wct + (size_t)(kb + t)*4);
    s += y0[t]*wv;
  }
#pragma unroll
  for (int t = 0; t < 4; ++t){
    f32x4 wv = *(const f32x4*)(wct + (size_t)(kb + 4 + t)*4);
    s += y1[t]*wv;
  }
#pragma unroll
  for (int o = 0; o < 4; ++o){
    float v = s[o];
#pragma unroll
    for (int d = 32; d > 0; d >>= 1) v += __shfl_xor(v, d);
    if (lane == 0) out[(size_t)orig*OUTq + o] = v + bh2[ct*OUTq + o];
  }
}

// ---------------------------------------------------------------------------
extern "C" void kernel_launch(void* const* d_in, const int* in_sizes, int n_in,
                              void* d_out, int out_size, void* d_ws, size_t ws_size,
                              hipStream_t stream){
  (void)in_sizes; (void)n_in; (void)out_size;
  const float* state = (const float*)d_in[0];
  const int*   cVec  = (const int*)  d_in[1];
  const float* Wte   = (const float*)d_in[2];
  const float* Wb1   = (const float*)d_in[3];
  const float* bb1   = (const float*)d_in[4];
  const float* Wb2   = (const float*)d_in[5];
  const float* bb2   = (const float*)d_in[6];
  const float* Wh1   = (const float*)d_in[7];
  const float* bh1   = (const float*)d_in[8];
  const float* Wh2   = (const float*)d_in[9];
  const float* bh2   = (const float*)d_in[10];
  float* out = (float*)d_out;

  auto A = [](size_t x) -> size_t { return (x + 255) & ~(size_t)255; };
  auto mx = [](size_t a, size_t b) -> size_t { return a > b ? a : b; };

  const size_t pers = A((size_t)Bq*INP*2)          // sB
                    + A((size_t)Eq*H1q*INP*2)      // w1
                    + A((size_t)Cq*HHq*H2q*2)      // wh
                    + A((size_t)Bq*4) + 2*A(64);   // perm, cnt, poff

  // config ladder: (NB batch chunks, G experts per chunk), fastest first
  const int candNB[8] = {1, 1, 1, 1, 2, 4, 8, 16};
  const int candG [8] = {8, 4, 2, 1, 1, 1, 1, 1};
  int NB = 16, G = 1;
  for (int i = 0; i < 8; ++i){
    size_t Bc = (size_t)Bq / candNB[i];
    int g = candG[i];
    size_t need = pers
                + A((size_t)g*H2q*H1q*2)                        // w2 slice
                + mx(A((size_t)g*Bc*H1q*2), A(Bc*(size_t)HHq*4))// h ; y1p aliases
                + A(Bc*(size_t)H2q*2)                           // f
                + (g < 8 ? A(Bc*(size_t)H2q*4) : 0);            // f32f
    if (need <= ws_size){ NB = candNB[i]; G = candG[i]; break; }
  }
  const int Bc = Bq / NB;

  char* ws = (char*)d_ws;
  size_t p = 0;
  auto alloc = [&](size_t bytes) -> void* { void* r = ws + p; p += A(bytes); return r; };

  unsigned short* sB  = (unsigned short*)alloc((size_t)Bq*INP*2);
  unsigned short* w1B = (unsigned short*)alloc((size_t)Eq*H1q*INP*2);
  unsigned short* whB = (unsigned short*)alloc((size_t)Cq*HHq*H2q*2);
  int* perm = (int*)alloc((size_t)Bq*4);
  int* cnt  = (int*)alloc(64);
  int* poff = (int*)alloc(64);
  unsigned short* w2B = (unsigned short*)alloc((size_t)G*H2q*H1q*2);
  // region1: h while backbone+moe run; y1p afterwards (h dead before k_head1)
  char* r1 = (char*)alloc(mx(A((size_t)G*Bc*H1q*2), A((size_t)Bc*HHq*4)));
  unsigned short* hB = (unsigned short*)r1;
  float* y1p = (float*)r1;
  unsigned short* fB = (unsigned short*)alloc((size_t)Bc*H2q*2);
  float* f32f = (G < 8) ? (float*)alloc((size_t)Bc*H2q*4) : (float*)fB; // unused if G==8

  const dim3 tb(32, 8, 1);
  // Wh1 [C][1024k][512o] -> [C][512o][1024k]
  k_tcast<<<dim3(16, 32, 10), tb, 0, stream>>>(Wh1, whB, H2q, HHq, H2q);
  // Wb1 [E][39k][1024o] -> [E][1024o][64k] (zero-pad K)
  k_tcast<<<dim3(32, 2, 8), tb, 0, stream>>>(Wb1, w1B, INq, H1q, INP);
  k_scast<<<(Bq*INP + 255)/256, 256, 0, stream>>>(state, sB);

  const int nch = Eq / G;
  for (int nb = 0; nb < NB; ++nb){
    const int b0 = nb*Bc;
    k_bucket<<<1, 1024, 0, stream>>>(cVec, b0, Bc, cnt, poff, perm);
    for (int ec = 0; ec < nch; ++ec){
      const int e0 = ec*G;
      // Wb2 slice [G][1024k][1024o] -> [G][1024o][1024k]
      k_tcast<<<dim3(32, 32, G), tb, 0, stream>>>(Wb2 + (size_t)e0*H1q*H2q, w2B,
                                                  H1q, H2q, H1q);
      k_h  <<<dim3(Bc/128, 8, G), 256, 0, stream>>>(sB, w1B, bb1, hB, e0, b0, Bc);
      k_moe<<<dim3(Bc/128, 8), 256, 0, stream>>>(hB, w2B, Wte, cVec, bb2, f32f, fB,
                                                 e0, G, ec == 0 ? 1 : 0,
                                                 ec == nch - 1 ? 1 : 0, b0, Bc);
    }
    k_head1<<<dim3(Bc/128, 10, 4), 256, 0, stream>>>(fB, whB, bh1, perm, cnt, poff, y1p);
    k_head2<<<Bc/4, 256, 0, stream>>>(y1p, Wh2, bh2, perm, cVec, out, b0);
  }
}

// Round 8
// 693.125 us; speedup vs baseline: 1.9714x; 1.0130x over previous
//
#include <hip/hip_runtime.h>
#include <stdint.h>

#define DEVI __device__ __forceinline__

typedef float f32x4 __attribute__((ext_vector_type(4)));
typedef short bf16x8 __attribute__((ext_vector_type(8)));

constexpr int Bq  = 16384;  // batch
constexpr int Eq  = 8;      // experts
constexpr int Cq  = 10;     // contexts
constexpr int INq = 39;     // obs dim
constexpr int INP = 64;     // padded obs dim
constexpr int H1q = 1024;
constexpr int H2q = 1024;
constexpr int HHq = 512;
constexpr int OUTq = 4;

DEVI unsigned short bf16_rne(float x){
  unsigned u = __builtin_bit_cast(unsigned, x);
  u += 0x7FFFu + ((u >> 16) & 1u);
  return (unsigned short)(u >> 16);
}
DEVI float bf16f(unsigned short h){
  unsigned u = ((unsigned)h) << 16;
  return __builtin_bit_cast(float, u);
}

// async global->LDS DMA, 16B/lane; LDS dest wave-uniform base (+lane*16 implicit)
DEVI void dma16(const unsigned short* g, unsigned short* l){
  __builtin_amdgcn_global_load_lds(
      (const __attribute__((address_space(1))) unsigned int*)g,
      (__attribute__((address_space(3))) unsigned int*)l,
      16, 0, 0);
}

// ---------------------------------------------------------------------------
// One BK=32 K-step of the 128x128 (2x2 waves, 64x64/wave) bf16 GEMM.
// LDS per buffer: 2 tiles [128 rows][32 k] bf16 (8KB): tile0=A, tile1=B.
// k-chunk slot XOR-swizzle: slot = chunk ^ ((row>>1)&3), applied on BOTH the
// global source address (DMA writer) and the LDS read (guide rule #21).
// ---------------------------------------------------------------------------
DEVI void mfma_step1(const unsigned short* lsb, int lane, int wm, int wn, f32x4 acc[4][4]){
  const int g = lane >> 4;
  bf16x8 a[4], b[4];
#pragma unroll
  for (int mf = 0; mf < 4; ++mf){
    int r = wm*64 + mf*16 + (lane & 15);
    a[mf] = *(const bf16x8*)(lsb + r*32 + (g ^ ((r >> 1) & 3))*8);
  }
#pragma unroll
  for (int nf = 0; nf < 4; ++nf){
    int r = wn*64 + nf*16 + (lane & 15);
    b[nf] = *(const bf16x8*)(lsb + 4096 + r*32 + (g ^ ((r >> 1) & 3))*8);
  }
#pragma unroll
  for (int nf = 0; nf < 4; ++nf)
#pragma unroll
    for (int mf = 0; mf < 4; ++mf)
      acc[mf][nf] = __builtin_amdgcn_mfma_f32_16x16x32_bf16(a[mf], b[nf], acc[mf][nf], 0, 0, 0);
}

// ---------------------------------------------------------------------------
// prep: transpose + cast: src fp32 [Z][R][Cc] -> dst bf16 [Z][Cc][Rpad]
// ---------------------------------------------------------------------------
__global__ void k_tcast(const float* __restrict__ src, unsigned short* __restrict__ dst,
                        int R, int Cc, int Rpad){
  __shared__ float t[32][33];
  const int z = blockIdx.z;
  const int c0 = blockIdx.x*32, r0 = blockIdx.y*32;
  const float* s = src + (size_t)z*R*Cc;
#pragma unroll
  for (int i = 0; i < 4; ++i){
    int r = r0 + threadIdx.y + i*8;
    int cc = c0 + threadIdx.x;
    float v = (r < R && cc < Cc) ? s[(size_t)r*Cc + cc] : 0.f;
    t[threadIdx.y + i*8][threadIdx.x] = v;
  }
  __syncthreads();
  const size_t dbase = (size_t)z*Cc*Rpad;
#pragma unroll
  for (int i = 0; i < 4; ++i){
    int cc = c0 + threadIdx.y + i*8;
    int r  = r0 + threadIdx.x;
    if (cc < Cc && r < Rpad)
      dst[dbase + (size_t)cc*Rpad + r] = bf16_rne(t[threadIdx.x][threadIdx.y + i*8]);
  }
}

// prep: state [B][39] fp32 -> padded bf16 [B][64]
__global__ void k_scast(const float* __restrict__ st, unsigned short* __restrict__ sB){
  int i = blockIdx.x*blockDim.x + threadIdx.x;
  if (i >= Bq*INP) return;
  int b = i >> 6, kk = i & 63;
  sB[i] = bf16_rne((kk < INq) ? st[b*INq + kk] : 0.f);
}

// bucket chunk rows [b0,b0+Bc) by context: cnt[10], poff[10], perm[Bc] (LOCAL ids)
__global__ void k_bucket(const int* __restrict__ c, int b0, int Bc,
                         int* __restrict__ cnt, int* __restrict__ poff,
                         int* __restrict__ perm){
  __shared__ int lcnt[Cq];
  __shared__ int lcur[Cq];
  const int tid = threadIdx.x;
  if (tid < Cq) lcnt[tid] = 0;
  __syncthreads();
  for (int i = tid; i < Bc; i += blockDim.x) atomicAdd(&lcnt[c[b0 + i]], 1);
  __syncthreads();
  if (tid == 0){
    int s = 0;
    for (int k = 0; k < Cq; ++k){ poff[k] = s; lcur[k] = s; cnt[k] = lcnt[k]; s += lcnt[k]; }
  }
  __syncthreads();
  for (int i = tid; i < Bc; i += blockDim.x){
    int p = atomicAdd(&lcur[c[b0 + i]], 1);
    perm[p] = i;
  }
}

// ---------------------------------------------------------------------------
// K1: h[el][row][o] = relu(state[b0+row] @ Wb1[e0+el] + bb1) in bf16.
// K=64 (2 BK=32 steps). grid (bt=Bc/128, ot=8, el=G). 2-buffer (tiny K).
// ---------------------------------------------------------------------------
__global__ __launch_bounds__(256, 2)
void k_h(const unsigned short* __restrict__ sB, const unsigned short* __restrict__ w1B,
         const float* __restrict__ bb1, unsigned short* __restrict__ hB,
         int e0, int b0, int Bc){
  __shared__ unsigned short ls[2][2][4096];
  const int tid = threadIdx.x, lane = tid & 63, wid = tid >> 6;
  const int wm = wid >> 1, wn = wid & 1;
  const int bt = blockIdx.x, ot = blockIdx.y, el = blockIdx.z;
  const int ge = e0 + el;
  const int rl = lane >> 2, cs = lane & 3;
  const int corig = cs ^ ((rl >> 1) & 3);

  const f32x4 vz = {0.f, 0.f, 0.f, 0.f};
  f32x4 acc[4][4];
#pragma unroll
  for (int a = 0; a < 4; ++a)
#pragma unroll
    for (int b = 0; b < 4; ++b) acc[a][b] = vz;

  auto stage = [&](int buf, int s){
    const int k0 = s*32;
    const int half = wid & 1;
    if (wid < 2){
#pragma unroll
      for (int i = 0; i < 4; ++i){
        int seg = half*4 + i;
        int r = b0 + bt*128 + seg*16 + rl;
        dma16(sB + (size_t)r*INP + k0 + corig*8, &ls[buf][0][0] + seg*512);
      }
    } else {
#pragma unroll
      for (int i = 0; i < 4; ++i){
        int seg = half*4 + i;
        int r = ge*H1q + ot*128 + seg*16 + rl;
        dma16(w1B + (size_t)r*INP + k0 + corig*8, &ls[buf][1][0] + seg*512);
      }
    }
  };

  stage(0, 0);
  for (int s = 0; s < 2; ++s){
    __syncthreads();                    // drains DMA (vmcnt 0) + publishes LDS
    if (s == 0) stage(1, 1);
    mfma_step1(&ls[s][0][0], lane, wm, wn, acc);
  }

  const int rbase = bt*128 + wm*64 + 4*(lane >> 4);   // local row
  const int cbase = ot*128 + wn*64 + (lane & 15);
#pragma unroll
  for (int nf = 0; nf < 4; ++nf){
    const int col = cbase + nf*16;
    const float bias = bb1[ge*H1q + col];
#pragma unroll
    for (int mf = 0; mf < 4; ++mf){
#pragma unroll
      for (int j = 0; j < 4; ++j){
        int row = rbase + mf*16 + j;
        hB[((size_t)el*Bc + row)*H1q + col] = bf16_rne(fmaxf(acc[mf][nf][j] + bias, 0.f));
      }
    }
  }
}

// ---------------------------------------------------------------------------
// K2 (dominant): feat = h_el @ Wb2T[el]; facc += Wte[ge,c[b]]*relu(feat+bb2).
// T4 counted-vmcnt 3-buffer pipeline: stages stay in flight across raw
// s_barriers; per-wave 4 DMA/stage -> vmcnt(4) = one stage still outstanding.
// All stray vmem (Wte, cidx, bb2, facc) hoisted to prologue so the in-loop
// vmcnt counts ONLY stage DMAs. bb2 cached in LDS as bf16 (ds_read, lgkm).
// grid (bt=Bc/128, ot=8): bt-major -> xcd=bt%8 shares L2 copy of h stripe.
// ---------------------------------------------------------------------------
__global__ __launch_bounds__(256, 2)
void k_moe(const unsigned short* __restrict__ hB, const unsigned short* __restrict__ w2B,
           const float* __restrict__ Wte, const int* __restrict__ cIn,
           const float* __restrict__ bb2, float* __restrict__ f32f,
           unsigned short* __restrict__ fB,
           int e0, int G, int first, int last, int b0, int Bc){
  __shared__ unsigned short ls[3][2][4096];   // 48KB: 3 buffers x (A,B) tiles
  __shared__ float lWte[Eq*Cq];
  __shared__ unsigned short lbb2[Eq*128];     // bias slice for this ot, bf16
  const int tid = threadIdx.x, lane = tid & 63, wid = tid >> 6;
  const int wm = wid >> 1, wn = wid & 1;
  const int bt = blockIdx.x, ot = blockIdx.y;

  if (tid < Eq*Cq) lWte[tid] = Wte[tid];
  for (int i = tid; i < G*128; i += 256)
    lbb2[i] = bf16_rne(bb2[(size_t)(e0 + (i >> 7))*H2q + ot*128 + (i & 127)]);

  const int rl = lane >> 2, cs = lane & 3;
  const int corig = cs ^ ((rl >> 1) & 3);
  const int rbase = bt*128 + wm*64 + 4*(lane >> 4);   // local row
  const int cbase = ot*128 + wn*64 + (lane & 15);
  const int cloc  = wn*64 + (lane & 15);              // column within ot tile

  int cidx[16];
#pragma unroll
  for (int mf = 0; mf < 4; ++mf)
#pragma unroll
    for (int j = 0; j < 4; ++j)
      cidx[mf*4 + j] = cIn[b0 + rbase + mf*16 + j];

  const f32x4 vz = {0.f, 0.f, 0.f, 0.f};
  f32x4 acc[4][4], facc[4][4];
#pragma unroll
  for (int a = 0; a < 4; ++a)
#pragma unroll
    for (int b = 0; b < 4; ++b){ acc[a][b] = vz; facc[a][b] = vz; }

  if (!first){
#pragma unroll
    for (int mf = 0; mf < 4; ++mf)
#pragma unroll
      for (int nf = 0; nf < 4; ++nf)
#pragma unroll
        for (int j = 0; j < 4; ++j)
          facc[mf][nf][j] = f32f[(size_t)(rbase + mf*16 + j)*H2q + cbase + nf*16];
  }

  auto stage = [&](int buf, int s){
    const int el = s >> 5;
    const int k0 = (s & 31)*32;
    const int half = wid & 1;
    if (wid < 2){
#pragma unroll
      for (int i = 0; i < 4; ++i){
        int seg = half*4 + i;
        int r = bt*128 + seg*16 + rl;
        dma16(hB + ((size_t)el*Bc + r)*H1q + k0 + corig*8, &ls[buf][0][0] + seg*512);
      }
    } else {
#pragma unroll
      for (int i = 0; i < 4; ++i){
        int seg = half*4 + i;
        int r = el*H2q + ot*128 + seg*16 + rl;   // slot-local expert index
        dma16(w2B + (size_t)r*H1q + k0 + corig*8, &ls[buf][1][0] + seg*512);
      }
    }
  };

  const int total = G*32;
  // prologue: two stages in flight; wait stage0 (+ all stray vmem + LDS init)
  stage(0, 0);
  stage(1, 1);
  asm volatile("s_waitcnt vmcnt(4) lgkmcnt(0)" ::: "memory");
  asm volatile("s_barrier" ::: "memory");

  int cur = 0;
  for (int s = 0; s < total; ++s){
    if (s + 2 < total){
      int b2 = cur + 2; if (b2 >= 3) b2 -= 3;
      stage(b2, s + 2);                 // issue 2-ahead; overlaps this+next MFMA
    }
    mfma_step1(&ls[cur][0][0], lane, wm, wn, acc);
    if ((s & 31) == 31){                // expert boundary: combine (VALU, overlaps DMA)
      const int ge = e0 + (s >> 5);
      const int el = s >> 5;
#pragma unroll
      for (int nf = 0; nf < 4; ++nf){
        const float bias = bf16f(lbb2[el*128 + cloc + nf*16]);
#pragma unroll
        for (int mf = 0; mf < 4; ++mf){
          f32x4 v = acc[mf][nf];
          acc[mf][nf] = vz;
#pragma unroll
          for (int j = 0; j < 4; ++j){
            float w = lWte[ge*Cq + cidx[mf*4 + j]];
            facc[mf][nf][j] += w * fmaxf(v[j] + bias, 0.f);
          }
        }
      }
    }
    // ensure stage(s+1) landed; keep stage(s+2) in flight (counted, NOT 0)
    if (s + 2 < total) asm volatile("s_waitcnt vmcnt(4)" ::: "memory");
    else               asm volatile("s_waitcnt vmcnt(0)" ::: "memory");
    asm volatile("s_barrier" ::: "memory");
    cur = (cur + 1 == 3) ? 0 : cur + 1;
  }

#pragma unroll
  for (int mf = 0; mf < 4; ++mf)
#pragma unroll
    for (int nf = 0; nf < 4; ++nf)
#pragma unroll
      for (int j = 0; j < 4; ++j){
        const size_t o = (size_t)(rbase + mf*16 + j)*H2q + cbase + nf*16;
        if (last) fB[o] = bf16_rne(fmaxf(facc[mf][nf][j], 0.f));
        else      f32f[o] = facc[mf][nf][j];
      }
}

// ---------------------------------------------------------------------------
// K3: per-context gathered GEMM y1p[pos] = relu(f[perm[pos]] @ Wh1[ct] + bh1)
// grid (tile=Bc/128, ct=10, ot=4); blocks past cnt[ct] exit. perm/f rows LOCAL.
// ---------------------------------------------------------------------------
__global__ __launch_bounds__(256, 2)
void k_head1(const unsigned short* __restrict__ fB, const unsigned short* __restrict__ whB,
             const float* __restrict__ bh1,
             const int* __restrict__ perm, const int* __restrict__ cnt,
             const int* __restrict__ poff, float* __restrict__ y1p){
  __shared__ unsigned short ls[2][2][4096];
  const int tile = blockIdx.x, ct = blockIdx.y, ot = blockIdx.z;
  const int n = cnt[ct];
  const int rem = n - tile*128;
  if (rem <= 0) return;
  const int tid = threadIdx.x, lane = tid & 63, wid = tid >> 6;
  const int wm = wid >> 1, wn = wid & 1;
  const int rl = lane >> 2, cs = lane & 3;
  const int corig = cs ^ ((rl >> 1) & 3);
  const int base = poff[ct] + tile*128;

  int prow[4];
#pragma unroll
  for (int i = 0; i < 4; ++i){
    int seg = (wid & 1)*4 + i;
    int lr = seg*16 + rl;
    prow[i] = perm[base + (lr < rem ? lr : 0)];
  }

  const f32x4 vz = {0.f, 0.f, 0.f, 0.f};
  f32x4 acc[4][4];
#pragma unroll
  for (int a = 0; a < 4; ++a)
#pragma unroll
    for (int b = 0; b < 4; ++b) acc[a][b] = vz;

  auto stage = [&](int buf, int s){
    const int k0 = s*32;
    const int half = wid & 1;
    if (wid < 2){
#pragma unroll
      for (int i = 0; i < 4; ++i){
        int seg = half*4 + i;
        dma16(fB + (size_t)prow[i]*H2q + k0 + corig*8, &ls[buf][0][0] + seg*512);
      }
    } else {
#pragma unroll
      for (int i = 0; i < 4; ++i){
        int seg = half*4 + i;
        int r = ct*HHq + ot*128 + seg*16 + rl;
        dma16(whB + (size_t)r*H2q + k0 + corig*8, &ls[buf][1][0] + seg*512);
      }
    }
  };

  stage(0, 0);
  for (int s = 0; s < 32; ++s){
    __syncthreads();
    if (s + 1 < 32) stage((s + 1) & 1, s + 1);
    mfma_step1(&ls[s & 1][0][0], lane, wm, wn, acc);
  }

  const int rloc = wm*64 + 4*(lane >> 4);
  const int cbase = ot*128 + wn*64 + (lane & 15);
#pragma unroll
  for (int nf = 0; nf < 4; ++nf){
    const int col = cbase + nf*16;
    const float bias = bh1[ct*HHq + col];
#pragma unroll
    for (int mf = 0; mf < 4; ++mf){
#pragma unroll
      for (int j = 0; j < 4; ++j){
        int lr = rloc + mf*16 + j;
        if (lr < rem)
          y1p[(size_t)(base + lr)*HHq + col] = fmaxf(acc[mf][nf][j] + bias, 0.f);
      }
    }
  }
}

// K4: a = y1 @ Wh2[ct] + bh2[ct], one wave per sample, scatter to d_out. (fp32)
__global__ void k_head2(const float* __restrict__ y1p, const float* __restrict__ Wh2,
                        const float* __restrict__ bh2, const int* __restrict__ perm,
                        const int* __restrict__ cIn, float* __restrict__ out, int b0){
  const int tid = threadIdx.x, lane = tid & 63, w = tid >> 6;
  const int pos = blockIdx.x*4 + w;
  const int orig = b0 + perm[pos];
  const int ct = cIn[orig];
  const float* yrow = y1p + (size_t)pos*HHq;
  const float* wct  = Wh2 + (size_t)ct*HHq*OUTq;
  f32x4 s = {0.f, 0.f, 0.f, 0.f};
  const int kb = lane*8;
  f32x4 y0 = *(const f32x4*)(yrow + kb);
  f32x4 y1 = *(const f32x4*)(yrow + kb + 4);
#pragma unroll
  for (int t = 0; t < 4; ++t){
    f32x4 wv = *(const f32x4*)(wct + (size_t)(kb + t)*4);
    s += y0[t]*wv;
  }
#pragma unroll
  for (int t = 0; t < 4; ++t){
    f32x4 wv = *(const f32x4*)(wct + (size_t)(kb + 4 + t)*4);
    s += y1[t]*wv;
  }
#pragma unroll
  for (int o = 0; o < 4; ++o){
    float v = s[o];
#pragma unroll
    for (int d = 32; d > 0; d >>= 1) v += __shfl_xor(v, d);
    if (lane == 0) out[(size_t)orig*OUTq + o] = v + bh2[ct*OUTq + o];
  }
}

// ---------------------------------------------------------------------------
extern "C" void kernel_launch(void* const* d_in, const int* in_sizes, int n_in,
                              void* d_out, int out_size, void* d_ws, size_t ws_size,
                              hipStream_t stream){
  (void)in_sizes; (void)n_in; (void)out_size;
  const float* state = (const float*)d_in[0];
  const int*   cVec  = (const int*)  d_in[1];
  const float* Wte   = (const float*)d_in[2];
  const float* Wb1   = (const float*)d_in[3];
  const float* bb1   = (const float*)d_in[4];
  const float* Wb2   = (const float*)d_in[5];
  const float* bb2   = (const float*)d_in[6];
  const float* Wh1   = (const float*)d_in[7];
  const float* bh1   = (const float*)d_in[8];
  const float* Wh2   = (const float*)d_in[9];
  const float* bh2   = (const float*)d_in[10];
  float* out = (float*)d_out;

  auto A = [](size_t x) -> size_t { return (x + 255) & ~(size_t)255; };
  auto mx = [](size_t a, size_t b) -> size_t { return a > b ? a : b; };

  const size_t pers = A((size_t)Bq*INP*2)          // sB
                    + A((size_t)Eq*H1q*INP*2)      // w1
                    + A((size_t)Cq*HHq*H2q*2)      // wh
                    + A((size_t)Bq*4) + 2*A(64);   // perm, cnt, poff

  // ladder: prefer G=8 (no f32f round-trip) at smallest NB; then G<8 fallback
  const int candNB[9] = {1, 2, 4, 8, 16, 16, 16, 16, 16};
  const int candG [9] = {8, 8, 8, 8, 16==16?8:8, 4, 2, 1, 1};
  int NB = 16, G = 1;
  for (int i = 0; i < 9; ++i){
    size_t Bc = (size_t)Bq / candNB[i];
    int g = candG[i];
    size_t need = pers
                + A((size_t)g*H2q*H1q*2)                          // w2 slice
                + mx(A((size_t)g*Bc*H1q*2), A(Bc*(size_t)HHq*4))  // h ; y1p alias
                + A(Bc*(size_t)H2q*2)                             // f
                + (g < 8 ? A(Bc*(size_t)H2q*4) : 0);              // f32f
    if (need <= ws_size){ NB = candNB[i]; G = g; break; }
  }
  const int Bc = Bq / NB;

  char* ws = (char*)d_ws;
  size_t p = 0;
  auto alloc = [&](size_t bytes) -> void* { void* r = ws + p; p += A(bytes); return r; };

  unsigned short* sB  = (unsigned short*)alloc((size_t)Bq*INP*2);
  unsigned short* w1B = (unsigned short*)alloc((size_t)Eq*H1q*INP*2);
  unsigned short* whB = (unsigned short*)alloc((size_t)Cq*HHq*H2q*2);
  int* perm = (int*)alloc((size_t)Bq*4);
  int* cnt  = (int*)alloc(64);
  int* poff = (int*)alloc(64);
  unsigned short* w2B = (unsigned short*)alloc((size_t)G*H2q*H1q*2);
  // region1: h while backbone+moe run; y1p afterwards (h dead before k_head1)
  char* r1 = (char*)alloc(mx(A((size_t)G*Bc*H1q*2), A((size_t)Bc*HHq*4)));
  unsigned short* hB = (unsigned short*)r1;
  float* y1p = (float*)r1;
  unsigned short* fB = (unsigned short*)alloc((size_t)Bc*H2q*2);
  float* f32f = (G < 8) ? (float*)alloc((size_t)Bc*H2q*4) : (float*)fB; // unused if G==8

  const dim3 tb(32, 8, 1);
  // Wh1 [C][1024k][512o] -> [C][512o][1024k]
  k_tcast<<<dim3(16, 32, 10), tb, 0, stream>>>(Wh1, whB, H2q, HHq, H2q);
  // Wb1 [E][39k][1024o] -> [E][1024o][64k] (zero-pad K)
  k_tcast<<<dim3(32, 2, 8), tb, 0, stream>>>(Wb1, w1B, INq, H1q, INP);
  k_scast<<<(Bq*INP + 255)/256, 256, 0, stream>>>(state, sB);
  if (G == Eq)   // all experts fit: transpose w2 once, outside the nb loop
    k_tcast<<<dim3(32, 32, Eq), tb, 0, stream>>>(Wb2, w2B, H1q, H2q, H1q);

  const int nch = Eq / G;
  for (int nb = 0; nb < NB; ++nb){
    const int b0 = nb*Bc;
    k_bucket<<<1, 1024, 0, stream>>>(cVec, b0, Bc, cnt, poff, perm);
    for (int ec = 0; ec < nch; ++ec){
      const int e0 = ec*G;
      if (G < Eq)  // per-chunk Wb2 slice transpose
        k_tcast<<<dim3(32, 32, G), tb, 0, stream>>>(Wb2 + (size_t)e0*H1q*H2q, w2B,
                                                    H1q, H2q, H1q);
      k_h  <<<dim3(Bc/128, 8, G), 256, 0, stream>>>(sB, w1B, bb1, hB, e0, b0, Bc);
      k_moe<<<dim3(Bc/128, 8), 256, 0, stream>>>(hB, w2B, Wte, cVec, bb2, f32f, fB,
                                                 e0, G, ec == 0 ? 1 : 0,
                                                 ec == nch - 1 ? 1 : 0, b0, Bc);
    }
    k_head1<<<dim3(Bc/128, 10, 4), 256, 0, stream>>>(fB, whB, bh1, perm, cnt, poff, y1p);
    k_head2<<<Bc/4, 256, 0, stream>>>(y1p, Wh2, bh2, perm, cVec, out, b0);
  }
}